// Round 5
// baseline (130.584 us; speedup 1.0000x reference)
//
#include <hip/hip_runtime.h>
#include <math.h>

// ---------------- workspace layout (bytes) ----------------
// [0)            double sum
// [16)           unsigned minkey[64]
// [16+256)       unsigned maxkey[64]
// [16+512)       float u7[7]   (separable 1-D gaussian weights)

__device__ __forceinline__ unsigned fkey(float f) {
    unsigned u = __float_as_uint(f);
    return (u & 0x80000000u) ? ~u : (u | 0x80000000u);
}
__device__ __forceinline__ float funkey(unsigned k) {
    return __uint_as_float((k & 0x80000000u) ? (k & 0x7FFFFFFFu) : ~k);
}

__global__ void init_ws(const float* __restrict__ w, float* __restrict__ u7,
                        unsigned* __restrict__ mink, unsigned* __restrict__ maxk,
                        double* __restrict__ sum) {
    int t = threadIdx.x;
    if (t == 0) *sum = 0.0;
    if (t < 64) { mink[t] = 0xFFFFFFFFu; maxk[t] = 0u; }
    if (t < 7) {
        float s = 0.f;
        for (int j = 0; j < 7; ++j) s += w[t * 7 + j];
        u7[t] = s;  // row sums of normalized 2-D window == 1-D weights
    }
}

// per-batch min/max of Y. 16 blocks per batch, 256 threads, float4 loads.
__global__ __launch_bounds__(256) void minmax_kernel(const float4* __restrict__ Y,
                                                     unsigned* __restrict__ mink,
                                                     unsigned* __restrict__ maxk) {
    int b = blockIdx.x >> 4, ch = blockIdx.x & 15;
    const float4* p = Y + (size_t)b * 65536 + (size_t)ch * 4096 + threadIdx.x;
    float lmin = INFINITY, lmax = -INFINITY;
#pragma unroll
    for (int i = 0; i < 16; ++i) {
        float4 v = p[(size_t)i * 256];
        lmin = fminf(lmin, fminf(fminf(v.x, v.y), fminf(v.z, v.w)));
        lmax = fmaxf(lmax, fmaxf(fmaxf(v.x, v.y), fmaxf(v.z, v.w)));
    }
#pragma unroll
    for (int off = 32; off; off >>= 1) {
        lmin = fminf(lmin, __shfl_down(lmin, off));
        lmax = fmaxf(lmax, __shfl_down(lmax, off));
    }
    if ((threadIdx.x & 63) == 0) {
        atomicMin(&mink[b], fkey(lmin));
        atomicMax(&maxk[b], fkey(lmax));
    }
}

// ---------------------------------------------------------------------------
// Main SSIM kernel. Tile: FULL 512 cols x 32 rows, 2 cols/thread.
// Grid = 64 img * 16 rowstrips = 1024 blocks, 256 threads.
// LDS row entry e = col + 4 (float2 {x,y}); e 0..3 and 516..519 are constant
// zeros (written once). Thread t writes cols 2t,2t+1 as one float4
// (ds_write_b128, 16B aligned), reads 8 shared float2 taps serving both
// output columns. Same validated mod-7/mod-2 macro-literal schedule as r4
// (no runtime-indexed arrays -> no scratch).
// ---------------------------------------------------------------------------
__global__ __launch_bounds__(256) void ssim_kernel(const float* __restrict__ X,
                                                   const float* __restrict__ Yg,
                                                   const float* __restrict__ u7,
                                                   const unsigned* __restrict__ mink,
                                                   const unsigned* __restrict__ maxk,
                                                   double* __restrict__ sum) {
    __shared__ float4 s4[2][260];      // = float2[2][520], 16B-aligned
    __shared__ float warpsum[4];

    const int blk = blockIdx.x;
    const int b   = blk >> 4;          // image
    const int rs  = blk & 15;          // row strip
    const int r0  = rs << 5;
    const int t   = threadIdx.x;

    float u[7];
#pragma unroll
    for (int i = 0; i < 7; ++i) u[i] = u7[i];

    const float dr = funkey(maxk[b]) - funkey(mink[b]);
    float C1 = 0.01f * dr; C1 *= C1;
    float C2 = 0.03f * dr; C2 *= C2;
    const float cn = 49.f / 48.f;

    const float* __restrict__ Xb = X  + ((size_t)b << 18);
    const float* __restrict__ Yb = Yg + ((size_t)b << 18);

    // constant zero halo entries (float2 idx 0..3 and 516..519)
    if (t < 2) {
        float4 z = make_float4(0.f, 0.f, 0.f, 0.f);
        s4[0][t] = z; s4[1][t] = z;
        s4[0][258 + t] = z; s4[1][258 + t] = z;
    }

    float2 fx[2], fy[2];               // prefetch regs (by row parity, literal idx)
    // mod-7 rings, 5 channels x 2 output columns (literal idx only)
    float phx0[7], phy0[7], phxx0[7], phyy0[7], phxy0[7];
    float phx1[7], phy1[7], phxx1[7], phyy1[7], phxy1[7];
    float ssacc = 0.f;

#define LOADROW(P, JJ) do {                                                   \
    int r_ = r0 - 3 + (JJ);                                                   \
    if (r_ >= 0 && r_ < 512) {   /* block-uniform branch */                   \
        const float2* xp_ = (const float2*)(Xb + ((size_t)r_ << 9)) + t;      \
        const float2* yp_ = (const float2*)(Yb + ((size_t)r_ << 9)) + t;      \
        fx[(P)] = *xp_; fy[(P)] = *yp_;                                       \
    } else {                                                                  \
        fx[(P)] = make_float2(0.f, 0.f); fy[(P)] = make_float2(0.f, 0.f);     \
    }                                                                         \
} while (0)

// interleave {x,y} per column: float2 entry (2t+4)={x0,y0}, (2t+5)={x1,y1}
#define WRITEROW(P) do {                                                      \
    s4[(P)][t + 2] = make_float4(fx[(P)].x, fy[(P)].x, fx[(P)].y, fy[(P)].y); \
} while (0)

// taps: v_[k] = col 2t-3+k (entry 2t+1+k). out0 (col 2t): v_[k] w= u[k], k=0..6
// out1 (col 2t+1): v_[k] w= u[k-1], k=1..7. Squares computed once per tap.
#define HBLUR(BUF, SLOT) do {                                                 \
    const float2* sb_ = (const float2*)s4[(BUF)];                             \
    float2 v_[8];                                                             \
    _Pragma("unroll")                                                         \
    for (int k_ = 0; k_ < 8; ++k_) v_[k_] = sb_[(t << 1) + 1 + k_];           \
    float hx0_=0.f, hy0_=0.f, hxx0_=0.f, hyy0_=0.f, hxy0_=0.f;                \
    float hx1_=0.f, hy1_=0.f, hxx1_=0.f, hyy1_=0.f, hxy1_=0.f;                \
    _Pragma("unroll")                                                         \
    for (int k_ = 0; k_ < 8; ++k_) {                                          \
        float xv_ = v_[k_].x, yv_ = v_[k_].y;                                 \
        float xx_ = xv_ * xv_, yy_ = yv_ * yv_, xy_ = xv_ * yv_;              \
        if (k_ < 7) {                                                         \
            hx0_  = fmaf(u[k_], xv_, hx0_);                                   \
            hy0_  = fmaf(u[k_], yv_, hy0_);                                   \
            hxx0_ = fmaf(u[k_], xx_, hxx0_);                                  \
            hyy0_ = fmaf(u[k_], yy_, hyy0_);                                  \
            hxy0_ = fmaf(u[k_], xy_, hxy0_);                                  \
        }                                                                     \
        if (k_ > 0) {                                                         \
            hx1_  = fmaf(u[k_ - 1], xv_, hx1_);                               \
            hy1_  = fmaf(u[k_ - 1], yv_, hy1_);                               \
            hxx1_ = fmaf(u[k_ - 1], xx_, hxx1_);                              \
            hyy1_ = fmaf(u[k_ - 1], yy_, hyy1_);                              \
            hxy1_ = fmaf(u[k_ - 1], xy_, hxy1_);                              \
        }                                                                     \
    }                                                                         \
    phx0[(SLOT)] = hx0_; phy0[(SLOT)] = hy0_; phxx0[(SLOT)] = hxx0_;          \
    phyy0[(SLOT)] = hyy0_; phxy0[(SLOT)] = hxy0_;                             \
    phx1[(SLOT)] = hx1_; phy1[(SLOT)] = hy1_; phxx1[(SLOT)] = hxx1_;          \
    phyy1[(SLOT)] = hyy1_; phxy1[(SLOT)] = hxy1_;                             \
} while (0)

// vertical blur: tap k reads slot (J+1+k)%7 with weight u[k]
#define VS(a, J) fmaf(u[6], a[(J) % 7], fmaf(u[5], a[((J)+6) % 7],            \
               fmaf(u[4], a[((J)+5) % 7], fmaf(u[3], a[((J)+4) % 7],          \
               fmaf(u[2], a[((J)+3) % 7], fmaf(u[1], a[((J)+2) % 7],          \
               u[0] * a[((J)+1) % 7]))))))

#define SSIM1(mux, muy, mxx, myy, mxy) do {                                   \
    float mux2 = (mux) * (mux), muy2 = (muy) * (muy), muxy = (mux) * (muy);   \
    float sxx = ((mxx) - mux2) * cn;                                          \
    float syy = ((myy) - muy2) * cn;                                          \
    float sxy = ((mxy) - muxy) * cn;                                          \
    float num = (2.f * muxy + C1) * (2.f * sxy + C2);                         \
    float den = (mux2 + muy2 + C1) * (sxx + syy + C2);                        \
    ssacc = fmaf(num, __builtin_amdgcn_rcpf(den), ssacc);                     \
} while (0)

#define EMIT(J) do {                                                          \
    {                                                                         \
        float mux = VS(phx0, (J)), muy = VS(phy0, (J));                       \
        float mxx = VS(phxx0, (J)), myy = VS(phyy0, (J)), mxy = VS(phxy0, (J));\
        SSIM1(mux, muy, mxx, myy, mxy);                                       \
    }                                                                         \
    {                                                                         \
        float mux = VS(phx1, (J)), muy = VS(phy1, (J));                       \
        float mxx = VS(phxx1, (J)), myy = VS(phyy1, (J)), mxy = VS(phxy1, (J));\
        SSIM1(mux, muy, mxx, myy, mxy);                                       \
    }                                                                         \
} while (0)

#define PSTEP(J) do {                                                         \
    HBLUR((J) & 1, (J) % 7);                                                  \
    WRITEROW(((J) + 1) & 1);                                                  \
    LOADROW(((J) + 1) & 1, (J) + 3);                                          \
    __syncthreads();                                                          \
} while (0)

#define MSTEP(J) do {                                                         \
    HBLUR((J) & 1, (J) % 7);                                                  \
    EMIT(J);                                                                  \
    WRITEROW(((J) + 1) & 1);                                                  \
    LOADROW(((J) + 1) & 1, jb + (J) + 3);                                     \
    __syncthreads();                                                          \
} while (0)

#define MSTEP_NL(J) do {                                                      \
    HBLUR((J) & 1, (J) % 7);                                                  \
    EMIT(J);                                                                  \
    WRITEROW(((J) + 1) & 1);                                                  \
    __syncthreads();                                                          \
} while (0)

#define MSTEP_END(J) do {                                                     \
    HBLUR((J) & 1, (J) % 7);                                                  \
    EMIT(J);                                                                  \
} while (0)

    // pre-prologue: rows 0,1,2 in flight; row 0 staged to buf0
    LOADROW(0, 0);
    LOADROW(1, 1);
    WRITEROW(0);
    LOADROW(0, 2);
    __syncthreads();

    // prologue: rows 0..5 fill ring slots 0..5 (no outputs)
    PSTEP(0); PSTEP(1); PSTEP(2); PSTEP(3); PSTEP(4); PSTEP(5);

    // main: rows 6..33 (outputs 0..27)
    for (int g = 0; g < 2; ++g) {
        const int jb = 14 * g;
        MSTEP(6);  MSTEP(7);  MSTEP(8);  MSTEP(9);  MSTEP(10); MSTEP(11); MSTEP(12);
        MSTEP(13); MSTEP(14); MSTEP(15); MSTEP(16); MSTEP(17); MSTEP(18); MSTEP(19);
    }

    // tail: rows 34..37 (outputs 28..31)
    {
        const int jb = 28;
        MSTEP(6);        // row 34, loads row 37
        MSTEP_NL(7);     // row 35
        MSTEP_NL(8);     // row 36, stages row 37
        MSTEP_END(9);    // row 37
    }

#undef LOADROW
#undef WRITEROW
#undef HBLUR
#undef VS
#undef SSIM1
#undef EMIT
#undef PSTEP
#undef MSTEP
#undef MSTEP_NL
#undef MSTEP_END

    // block reduction: wave shuffle -> LDS -> one double atomic per block
#pragma unroll
    for (int off = 32; off; off >>= 1) ssacc += __shfl_down(ssacc, off);
    if ((t & 63) == 0) warpsum[t >> 6] = ssacc;
    __syncthreads();
    if (t == 0) {
        double sm = (double)warpsum[0] + (double)warpsum[1] +
                    (double)warpsum[2] + (double)warpsum[3];
        atomicAdd(sum, sm);
    }
}

__global__ void finalize_kernel(const double* __restrict__ sum, float* __restrict__ out) {
    out[0] = (float)(1.0 - (*sum) / (64.0 * 512.0 * 512.0));
}

extern "C" void kernel_launch(void* const* d_in, const int* in_sizes, int n_in,
                              void* d_out, int out_size, void* d_ws, size_t ws_size,
                              hipStream_t stream) {
    const float* X = (const float*)d_in[0];
    const float* Y = (const float*)d_in[1];
    const float* W = (const float*)d_in[2];

    char* ws = (char*)d_ws;
    double* sum = (double*)(ws + 0);
    unsigned* mink = (unsigned*)(ws + 16);
    unsigned* maxk = (unsigned*)(ws + 16 + 256);
    float* u7 = (float*)(ws + 16 + 512);

    init_ws<<<1, 64, 0, stream>>>(W, u7, mink, maxk, sum);
    minmax_kernel<<<1024, 256, 0, stream>>>((const float4*)Y, mink, maxk);
    ssim_kernel<<<1024, 256, 0, stream>>>(X, Y, u7, mink, maxk, sum);
    finalize_kernel<<<1, 1, 0, stream>>>(sum, (float*)d_out);
}

// Round 6
// 108.204 us; speedup vs baseline: 1.2068x; 1.2068x over previous
//
#include <hip/hip_runtime.h>
#include <math.h>

// ---------------- workspace layout (bytes) ----------------
// [0)            double sum
// [16)           unsigned minkey[64]
// [16+256)       unsigned maxkey[64]
// [16+512)       float u7[7]   (separable 1-D gaussian weights)

__device__ __forceinline__ unsigned fkey(float f) {
    unsigned u = __float_as_uint(f);
    return (u & 0x80000000u) ? ~u : (u | 0x80000000u);
}
__device__ __forceinline__ float funkey(unsigned k) {
    return __uint_as_float((k & 0x80000000u) ? (k & 0x7FFFFFFFu) : ~k);
}

__global__ void init_ws(const float* __restrict__ w, float* __restrict__ u7,
                        unsigned* __restrict__ mink, unsigned* __restrict__ maxk,
                        double* __restrict__ sum) {
    int t = threadIdx.x;
    if (t == 0) *sum = 0.0;
    if (t < 64) { mink[t] = 0xFFFFFFFFu; maxk[t] = 0u; }
    if (t < 7) {
        float s = 0.f;
        for (int j = 0; j < 7; ++j) s += w[t * 7 + j];
        u7[t] = s;  // row sums of normalized 2-D window == 1-D weights
    }
}

// per-batch min/max of Y. 16 blocks per batch, 256 threads, float4 loads.
__global__ __launch_bounds__(256) void minmax_kernel(const float4* __restrict__ Y,
                                                     unsigned* __restrict__ mink,
                                                     unsigned* __restrict__ maxk) {
    int b = blockIdx.x >> 4, ch = blockIdx.x & 15;
    const float4* p = Y + (size_t)b * 65536 + (size_t)ch * 4096 + threadIdx.x;
    float lmin = INFINITY, lmax = -INFINITY;
#pragma unroll
    for (int i = 0; i < 16; ++i) {
        float4 v = p[(size_t)i * 256];
        lmin = fminf(lmin, fminf(fminf(v.x, v.y), fminf(v.z, v.w)));
        lmax = fmaxf(lmax, fmaxf(fmaxf(v.x, v.y), fmaxf(v.z, v.w)));
    }
#pragma unroll
    for (int off = 32; off; off >>= 1) {
        lmin = fminf(lmin, __shfl_down(lmin, off));
        lmax = fmaxf(lmax, __shfl_down(lmax, off));
    }
    if ((threadIdx.x & 63) == 0) {
        atomicMin(&mink[b], fkey(lmin));
        atomicMax(&maxk[b], fkey(lmax));
    }
}

// ---------------------------------------------------------------------------
// Main SSIM kernel. Tile: 256 cols x 64 rows, 1 col/thread.
// Grid = 64 img * 2 colstrips * 8 rowstrips = 1024 blocks, 256 threads.
// 70 input rows/tile (j=0..69, image row r0-3+j), outputs j=6..69.
// 4-channel formulation: blur {x, y, q=x^2+y^2, xy}. den needs only sxx+syy =
// (blur(q) - mux^2 - muy^2)*cn, so one channel replaces xx,yy.
// Staging precomputes q,xy -> LDS float4/column; taps are contiguous
// ds_read_b128 (conflict-free; r5's conflicts came from STRIDED float2).
// Same validated mod-7/mod-2 macro-literal schedule as r4 (no runtime-indexed
// arrays -> no scratch).
// ---------------------------------------------------------------------------
__global__ __launch_bounds__(256, 4) void ssim_kernel(const float* __restrict__ X,
                                                      const float* __restrict__ Yg,
                                                      const float* __restrict__ u7,
                                                      const unsigned* __restrict__ mink,
                                                      const unsigned* __restrict__ maxk,
                                                      double* __restrict__ sum) {
    __shared__ float4 s4[2][262];      // L = col - c0 + 3, L in [0,261]
    __shared__ float warpsum[4];

    const int blk = blockIdx.x;
    const int b   = blk >> 4;          // image
    const int sub = blk & 15;
    const int cs  = sub & 1;           // col strip
    const int rs  = sub >> 1;          // row strip (0..7)
    const int c0  = cs << 8;
    const int r0  = rs << 6;
    const int t   = threadIdx.x;

    float u[7];
#pragma unroll
    for (int i = 0; i < 7; ++i) u[i] = u7[i];

    const float dr = funkey(maxk[b]) - funkey(mink[b]);
    float C1 = 0.01f * dr; C1 *= C1;
    float C2 = 0.03f * dr; C2 *= C2;
    const float cn  = 49.f / 48.f;
    const float cn2 = 2.f * cn;

    const float* __restrict__ Xb = X  + ((size_t)b << 18);
    const float* __restrict__ Yb = Yg + ((size_t)b << 18);

    const int  c    = c0 + t;                     // main col, always in-image
    const bool hasE = (t < 6);                    // halo: L 0..2, 259..261
    const int  eL   = (t < 3) ? t : (t + 256);
    const int  ecol = c0 + eL - 3;
    const bool eok  = (ecol >= 0) && (ecol < 512);
    const int  ec   = min(max(ecol, 0), 511);

    float fx[2], fy[2], ex[2], ey[2];             // prefetch regs (row parity)
    float phx[7], phy[7], phq[7], phxy[7];        // mod-7 ring, 4 channels
    float ssacc = 0.f;

#define LOADROW(P, JJ) do {                                                   \
    int r_ = r0 - 3 + (JJ);                                                   \
    if (r_ >= 0 && r_ < 512) {   /* block-uniform branch */                   \
        const float* xp_ = Xb + ((size_t)r_ << 9);                            \
        const float* yp_ = Yb + ((size_t)r_ << 9);                            \
        fx[(P)] = xp_[c]; fy[(P)] = yp_[c];                                   \
        if (hasE) { ex[(P)] = eok ? xp_[ec] : 0.f;                            \
                    ey[(P)] = eok ? yp_[ec] : 0.f; }                          \
    } else {                                                                  \
        fx[(P)] = 0.f; fy[(P)] = 0.f; ex[(P)] = 0.f; ey[(P)] = 0.f;           \
    }                                                                         \
} while (0)

#define WRITEROW(P) do {                                                      \
    float q_  = fmaf(fx[(P)], fx[(P)], fy[(P)] * fy[(P)]);                    \
    float xy_ = fx[(P)] * fy[(P)];                                            \
    s4[(P)][t + 3] = make_float4(fx[(P)], fy[(P)], q_, xy_);                  \
    if (hasE) {                                                               \
        float qe_  = fmaf(ex[(P)], ex[(P)], ey[(P)] * ey[(P)]);               \
        float xye_ = ex[(P)] * ey[(P)];                                       \
        s4[(P)][eL] = make_float4(ex[(P)], ey[(P)], qe_, xye_);               \
    }                                                                         \
} while (0)

#define HBLUR(BUF, SLOT) do {                                                 \
    float hx_ = 0.f, hy_ = 0.f, hq_ = 0.f, hxy_ = 0.f;                        \
    _Pragma("unroll")                                                         \
    for (int k_ = 0; k_ < 7; ++k_) {                                          \
        float4 v_ = s4[(BUF)][t + k_];                                        \
        hx_  = fmaf(u[k_], v_.x, hx_);                                        \
        hy_  = fmaf(u[k_], v_.y, hy_);                                        \
        hq_  = fmaf(u[k_], v_.z, hq_);                                        \
        hxy_ = fmaf(u[k_], v_.w, hxy_);                                       \
    }                                                                         \
    phx[(SLOT)] = hx_; phy[(SLOT)] = hy_;                                     \
    phq[(SLOT)] = hq_; phxy[(SLOT)] = hxy_;                                   \
} while (0)

// vertical blur: tap k reads slot (J+1+k)%7 with weight u[k]
#define VS(a, J) fmaf(u[6], a[(J) % 7], fmaf(u[5], a[((J)+6) % 7],            \
               fmaf(u[4], a[((J)+5) % 7], fmaf(u[3], a[((J)+4) % 7],          \
               fmaf(u[2], a[((J)+3) % 7], fmaf(u[1], a[((J)+2) % 7],          \
               u[0] * a[((J)+1) % 7]))))))

#define EMIT(J) do {                                                          \
    float mux = VS(phx, (J)), muy = VS(phy, (J));                             \
    float mq  = VS(phq, (J)), mxy = VS(phxy, (J));                            \
    float mux2 = mux * mux, muy2 = muy * muy, muxy = mux * muy;               \
    float m2 = mux2 + muy2;                                                   \
    float A_ = fmaf(muxy, 2.f, C1);          /* 2 muxy + C1        */         \
    float B_ = fmaf(mxy - muxy, cn2, C2);    /* 2 sxy + C2         */         \
    float D_ = m2 + C1;                                                       \
    float E_ = fmaf(mq - m2, cn, C2);        /* sxx + syy + C2     */         \
    ssacc = fmaf(A_ * B_, __builtin_amdgcn_rcpf(D_ * E_), ssacc);             \
} while (0)

#define PSTEP(J) do {                                                         \
    HBLUR((J) & 1, (J) % 7);                                                  \
    WRITEROW(((J) + 1) & 1);                                                  \
    LOADROW(((J) + 1) & 1, (J) + 3);                                          \
    __syncthreads();                                                          \
} while (0)

#define MSTEP(J) do {                                                         \
    HBLUR((J) & 1, (J) % 7);                                                  \
    EMIT(J);                                                                  \
    WRITEROW(((J) + 1) & 1);                                                  \
    LOADROW(((J) + 1) & 1, jb + (J) + 3);                                     \
    __syncthreads();                                                          \
} while (0)

#define MSTEP_NL(J) do {                                                      \
    HBLUR((J) & 1, (J) % 7);                                                  \
    EMIT(J);                                                                  \
    WRITEROW(((J) + 1) & 1);                                                  \
    __syncthreads();                                                          \
} while (0)

#define MSTEP_END(J) do {                                                     \
    HBLUR((J) & 1, (J) % 7);                                                  \
    EMIT(J);                                                                  \
} while (0)

    // pre-prologue: rows 0,1 loaded; row 0 staged to buf0; row 2 in flight
    LOADROW(0, 0);
    LOADROW(1, 1);
    WRITEROW(0);
    LOADROW(0, 2);
    __syncthreads();

    // prologue: rows 0..5 fill ring slots 0..5 (loads rows 3..8)
    PSTEP(0); PSTEP(1); PSTEP(2); PSTEP(3); PSTEP(4); PSTEP(5);

    // main: rows 6..61 (outputs 0..55); loads rows 9..64
    for (int g = 0; g < 4; ++g) {
        const int jb = 14 * g;
        MSTEP(6);  MSTEP(7);  MSTEP(8);  MSTEP(9);  MSTEP(10); MSTEP(11); MSTEP(12);
        MSTEP(13); MSTEP(14); MSTEP(15); MSTEP(16); MSTEP(17); MSTEP(18); MSTEP(19);
    }

    // tail: rows 62..69 (outputs 56..63); loads rows 65..69
    {
        const int jb = 56;
        MSTEP(6);        // row 62, loads 65
        MSTEP(7);        // row 63, loads 66
        MSTEP(8);        // row 64, loads 67
        MSTEP(9);        // row 65, loads 68
        MSTEP(10);       // row 66, loads 69
        MSTEP_NL(11);    // row 67
        MSTEP_NL(12);    // row 68, stages row 69
        MSTEP_END(13);   // row 69
    }

#undef LOADROW
#undef WRITEROW
#undef HBLUR
#undef VS
#undef EMIT
#undef PSTEP
#undef MSTEP
#undef MSTEP_NL
#undef MSTEP_END

    // block reduction: wave shuffle -> LDS -> one double atomic per block
#pragma unroll
    for (int off = 32; off; off >>= 1) ssacc += __shfl_down(ssacc, off);
    if ((t & 63) == 0) warpsum[t >> 6] = ssacc;
    __syncthreads();
    if (t == 0) {
        double sm = (double)warpsum[0] + (double)warpsum[1] +
                    (double)warpsum[2] + (double)warpsum[3];
        atomicAdd(sum, sm);
    }
}

__global__ void finalize_kernel(const double* __restrict__ sum, float* __restrict__ out) {
    out[0] = (float)(1.0 - (*sum) / (64.0 * 512.0 * 512.0));
}

extern "C" void kernel_launch(void* const* d_in, const int* in_sizes, int n_in,
                              void* d_out, int out_size, void* d_ws, size_t ws_size,
                              hipStream_t stream) {
    const float* X = (const float*)d_in[0];
    const float* Y = (const float*)d_in[1];
    const float* W = (const float*)d_in[2];

    char* ws = (char*)d_ws;
    double* sum = (double*)(ws + 0);
    unsigned* mink = (unsigned*)(ws + 16);
    unsigned* maxk = (unsigned*)(ws + 16 + 256);
    float* u7 = (float*)(ws + 16 + 512);

    init_ws<<<1, 64, 0, stream>>>(W, u7, mink, maxk, sum);
    minmax_kernel<<<1024, 256, 0, stream>>>((const float4*)Y, mink, maxk);
    ssim_kernel<<<1024, 256, 0, stream>>>(X, Y, u7, mink, maxk, sum);
    finalize_kernel<<<1, 1, 0, stream>>>(sum, (float*)d_out);
}